// Round 7
// baseline (850.117 us; speedup 1.0000x reference)
//
#include <hip/hip_runtime.h>
#include <stdint.h>

#define T_TOK 8192
#define DIM   1024
#define HID   2048
#define NE    8

#define BM 128
#define BN 128

#define GB_TOK 32  // tokens per gate block

typedef float floatx4 __attribute__((ext_vector_type(4)));
typedef short shortx8 __attribute__((ext_vector_type(8)));

__device__ __forceinline__ unsigned short f2bf(float f) {
  unsigned int u = __float_as_uint(f);
  unsigned int r = 0x7fffu + ((u >> 16) & 1u);
  return (unsigned short)((u + r) >> 16);
}

// ------------- transpose+cast: in [R][C] f32 -> out [C][R] bf16, blockIdx.z = expert -------------
__global__ __launch_bounds__(256) void transpose_cast_kernel(const float* __restrict__ in,
                                                             unsigned short* __restrict__ out,
                                                             int R, int C) {
  __shared__ float tile[32][33];
  const size_t eoff = (size_t)blockIdx.z * R * C;
  const float* ip = in + eoff;
  unsigned short* op = out + eoff;
  int c0 = blockIdx.x * 32, r0 = blockIdx.y * 32;
  int tx = threadIdx.x, ty = threadIdx.y;
#pragma unroll
  for (int i = 0; i < 4; i++)
    tile[ty + i * 8][tx] = ip[(size_t)(r0 + ty + i * 8) * C + (c0 + tx)];
  __syncthreads();
#pragma unroll
  for (int i = 0; i < 4; i++)
    op[(size_t)(c0 + ty + i * 8) * R + (r0 + tx)] = f2bf(tile[tx][ty + i * 8]);
}

// ---------------- gating: 32 tokens/block; also casts x -> bf16 ----------------
__global__ __launch_bounds__(256) void gate_kernel(const float* __restrict__ x,
                                                   const float* __restrict__ wg,
                                                   unsigned short* __restrict__ xb,
                                                   int* counts, int* top1cnt, float* ssum,
                                                   int* tok_list, float* wgt_list) {
  __shared__ int   lds_cnt[8];
  __shared__ int   lds_top1[8];
  __shared__ float lds_ssum[4][8];
  __shared__ int   tk_e[GB_TOK][2];
  __shared__ int   tk_r[GB_TOK][2];
  __shared__ float tk_w[GB_TOK][2];
  __shared__ int   base[8];

  const int tid = threadIdx.x;
  const int wave = tid >> 6;
  const int lane = tid & 63;

  if (tid < 8) { lds_cnt[tid] = 0; lds_top1[tid] = 0; }
  if (tid < 32) lds_ssum[tid >> 3][tid & 7] = 0.f;
  __syncthreads();

  float ssum_local[8];
#pragma unroll
  for (int e = 0; e < 8; e++) ssum_local[e] = 0.f;

  for (int it = 0; it < GB_TOK / 4; it++) {
    const int lt = it * 4 + wave;
    const int t = blockIdx.x * GB_TOK + lt;

    float acc[8];
#pragma unroll
    for (int e = 0; e < 8; e++) acc[e] = 0.f;
    const float* xr = x + (size_t)t * DIM;
    unsigned short* xw = xb + (size_t)t * DIM;
#pragma unroll
    for (int i = 0; i < 16; i++) {
      int d = i * 64 + lane;
      float xv = xr[d];
      xw[d] = f2bf(xv);  // fused f32->bf16 cast
      const float4* wr = reinterpret_cast<const float4*>(wg + d * 8);
      float4 w0 = wr[0], w1 = wr[1];
      acc[0] += xv * w0.x; acc[1] += xv * w0.y; acc[2] += xv * w0.z; acc[3] += xv * w0.w;
      acc[4] += xv * w1.x; acc[5] += xv * w1.y; acc[6] += xv * w1.z; acc[7] += xv * w1.w;
    }
#pragma unroll
    for (int e = 0; e < 8; e++) {
#pragma unroll
      for (int off = 32; off > 0; off >>= 1) acc[e] += __shfl_xor(acc[e], off, 64);
    }
    if (lane == 0) {
      float mx = acc[0];
#pragma unroll
      for (int e = 1; e < 8; e++) mx = fmaxf(mx, acc[e]);
      float s[8], sum = 0.f;
#pragma unroll
      for (int e = 0; e < 8; e++) { s[e] = expf(acc[e] - mx); sum += s[e]; }
      float inv = 1.f / sum;
#pragma unroll
      for (int e = 0; e < 8; e++) { s[e] *= inv; ssum_local[e] += s[e]; }
      // top-2 (strict > : ties -> lower index, matches lax.top_k)
      int i1 = 0;
#pragma unroll
      for (int e = 1; e < 8; e++) if (s[e] > s[i1]) i1 = e;
      int i2 = (i1 == 0) ? 1 : 0;
#pragma unroll
      for (int e = 0; e < 8; e++) if (e != i1 && s[e] > s[i2]) i2 = e;
      atomicAdd(&lds_top1[i1], 1);
      int r1 = atomicAdd(&lds_cnt[i1], 1);
      int r2 = atomicAdd(&lds_cnt[i2], 1);
      tk_e[lt][0] = i1; tk_r[lt][0] = r1; tk_w[lt][0] = s[i1];
      tk_e[lt][1] = i2; tk_r[lt][1] = r2; tk_w[lt][1] = s[i2];
    }
  }
  if (lane == 0) {
#pragma unroll
    for (int e = 0; e < 8; e++) lds_ssum[wave][e] = ssum_local[e];
  }
  __syncthreads();
  if (tid < 8) {
    base[tid] = atomicAdd(&counts[tid], lds_cnt[tid]);
    atomicAdd(&top1cnt[tid], lds_top1[tid]);
    atomicAdd(&ssum[tid],
              lds_ssum[0][tid] + lds_ssum[1][tid] + lds_ssum[2][tid] + lds_ssum[3][tid]);
  }
  __syncthreads();
  if (tid < GB_TOK * 2) {
    int lt = tid >> 1, k = tid & 1;
    int e = tk_e[lt][k];
    int pos = base[e] + tk_r[lt][k];
    tok_list[e * T_TOK + pos] = blockIdx.x * GB_TOK + lt;
    wgt_list[e * T_TOK + pos] = tk_w[lt][k];
  }
}

// ---------------- scan + l_aux + flat tile map (BM=128 tiles) ----------------
__global__ void scan_kernel(const int* counts, const int* top1cnt, const float* ssum,
                            int* h_off, int* tile_off, float* laux_out) {
  if (threadIdx.x == 0 && blockIdx.x == 0) {
    int off = 0, toff = 0;
    float l = 0.f;
    for (int e = 0; e < 8; e++) {
      h_off[e] = off;
      tile_off[e] = toff;
      off += counts[e];
      toff += (counts[e] + BM - 1) / BM;
      l += (ssum[e] / (float)T_TOK) * ((float)top1cnt[e] / (float)T_TOK);
    }
    tile_off[8] = toff;
    *laux_out = l * (float)NE;
  }
}

// ---------------- grouped GEMM: DIRECT-TO-FRAGMENT, zero LDS, zero barriers ----------------
// Key fact exploited: with row-major A (x_bf / h_buf) and K-major B (w1t / w2t), the MFMA
// 16x16x32 fragment for lane (quad,lm) is a CONTIGUOUS 16B of row [.. + lm] at k-offset
// quad*8 within each 32-k slice -> load fragments straight from global via
// global_load_dwordx4. No staging, no vmcnt(0) drains, no __syncthreads: each wave is an
// independent load->MFMA stream. The r0-r5 staging path was serialization-bound (~5x above
// every HW floor: MfmaUtil 18, L2 12%, conflicts 0); this removes the structure that caused it.
// Costs 2x logical read traffic (wave pairs no longer share a tile) - acceptable: 93% L2-hit
// (r6 FETCH=81MB) and 12% of L2 BW in use. XCD chunk swizzle retained (keeps traffic L2-local).
// Software pipeline: 1 step deep, named register sets (aR/bR vs aN/bN), fully static indexing.
// MODE 0: A = x_bf gathered via tok_list; epilogue relu(acc + b1) -> h_buf bf16 (stride N==HID)
// MODE 1: A = h_buf rows (h_off[e]+row);   epilogue atomicAdd(out[tok], w*(acc + b2))
template <int MODE>
__global__ __launch_bounds__(256, 2) void moe_gemm_kernel(
    const unsigned short* __restrict__ A_src, const unsigned short* __restrict__ B_src,
    const float* __restrict__ bias, const int* __restrict__ counts,
    const int* __restrict__ h_off, const int* __restrict__ tile_off,
    const int* __restrict__ tok_list, const float* __restrict__ wgt_list,
    unsigned short* __restrict__ h_out, float* __restrict__ out, int N, int K) {
  // ---- chunked XCD swizzle (bijective: grid size is a multiple of 8) ----
  const int ntx = N / BN;            // 16 (GEMM1) or 8 (GEMM2)
  const int cpx = ntx * 17;          // blocks per XCD chunk = ntx * 136 / 8
  const int bid = blockIdx.x;
  const int wg  = (bid & 7) * cpx + (bid >> 3);
  const int bt  = wg / ntx;          // flat M-tile
  const int nt  = wg - bt * ntx;     // N-tile (fastest within chunk)

  if (bt >= tile_off[8]) return;
  int e = 7;
#pragma unroll
  for (int q = 6; q >= 0; q--)
    if (bt < tile_off[q + 1]) e = q;
  const int n_e = counts[e];
  const int m0 = (bt - tile_off[e]) * BM;
  const int n0 = nt * BN;
  const int tid = threadIdx.x;

  const int lane = tid & 63;
  const int wv = tid >> 6;           // 0..3 (wave grid 2M x 2N)
  const int lm = lane & 15;
  const int quad = lane >> 4;
  const int wm = (wv >> 1) * 64;
  const int wn = (wv & 1) * 64;

  // per-lane fragment row base pointers (element units), incl. the quad's 8-elem k-offset
  const unsigned short* ap[4];
  const unsigned short* bp[4];
#pragma unroll
  for (int x = 0; x < 4; x++) {
    int gr = m0 + wm + x * 16 + lm;
    int safe = (gr < n_e) ? gr : (n_e - 1);   // clamp: garbage only feeds discarded C rows
    const unsigned short* abase;
    if (MODE == 0) {
      abase = A_src + (size_t)tok_list[e * T_TOK + safe] * K;
    } else {
      abase = A_src + (size_t)(h_off[e] + safe) * K;
    }
    ap[x] = abase + quad * 8;
    bp[x] = B_src + ((size_t)e * N + n0 + wn + x * 16 + lm) * K + quad * 8;
  }

  floatx4 acc[4][4];
#pragma unroll
  for (int mi = 0; mi < 4; mi++)
#pragma unroll
    for (int ni = 0; ni < 4; ni++) acc[mi][ni] = (floatx4){0.f, 0.f, 0.f, 0.f};

#define LOADF(Adst, Bdst, KO)                                                \
  do {                                                                       \
    _Pragma("unroll") for (int x_ = 0; x_ < 4; x_++) {                       \
      Adst[x_] = *reinterpret_cast<const shortx8*>(ap[x_] + (KO));           \
      Bdst[x_] = *reinterpret_cast<const shortx8*>(bp[x_] + (KO));           \
    }                                                                        \
  } while (0)

#define MFMAF(Aset, Bset)                                                    \
  do {                                                                       \
    _Pragma("unroll") for (int mi_ = 0; mi_ < 4; mi_++)                      \
      _Pragma("unroll") for (int ni_ = 0; ni_ < 4; ni_++)                    \
        acc[mi_][ni_] = __builtin_amdgcn_mfma_f32_16x16x32_bf16(             \
            Aset[mi_], Bset[ni_], acc[mi_][ni_], 0, 0, 0);                   \
  } while (0)

  // K-slices of 32; NS is even (32 for K=1024, 64 for K=2048).
  const int NS = K / 32;
  shortx8 aR[4], bR[4], aN[4], bN[4];

  LOADF(aR, bR, 0);
  for (int sb = 0; sb < NS / 2; ++sb) {
    const int ko = sb * 64;
    LOADF(aN, bN, ko + 32);               // prefetch slice 2sb+1 while computing 2sb
    MFMAF(aR, bR);
    const int ko2 = (ko + 64 < K) ? (ko + 64) : (K - 32);  // last iter: harmless reload
    LOADF(aR, bR, ko2);                   // prefetch slice 2sb+2 while computing 2sb+1
    MFMAF(aN, bN);
  }

  // epilogue: D row = quad*4 + r, col = lm (verified C/D layout)
#pragma unroll
  for (int mi = 0; mi < 4; mi++) {
#pragma unroll
    for (int r = 0; r < 4; r++) {
      int row = m0 + wm + mi * 16 + quad * 4 + r;
      if (row >= n_e) continue;
      if (MODE == 0) {
        size_t base = (size_t)(h_off[e] + row) * N;
#pragma unroll
        for (int ni = 0; ni < 4; ni++) {
          int col = n0 + wn + ni * 16 + lm;
          float v = acc[mi][ni][r] + bias[e * N + col];
          v = fmaxf(v, 0.f);
          h_out[base + col] = f2bf(v);
        }
      } else {
        int tok = tok_list[e * T_TOK + row];
        float wgt = wgt_list[e * T_TOK + row];
        size_t base = (size_t)tok * N;
#pragma unroll
        for (int ni = 0; ni < 4; ni++) {
          int col = n0 + wn + ni * 16 + lm;
          float v = wgt * (acc[mi][ni][r] + bias[e * N + col]);
          atomicAdd(&out[base + col], v);
        }
      }
    }
  }
#undef LOADF
#undef MFMAF
}

extern "C" void kernel_launch(void* const* d_in, const int* in_sizes, int n_in,
                              void* d_out, int out_size, void* d_ws, size_t ws_size,
                              hipStream_t stream) {
  const float* x  = (const float*)d_in[0];
  const float* wg = (const float*)d_in[1];
  const float* w1 = (const float*)d_in[2];
  const float* b1 = (const float*)d_in[3];
  const float* w2 = (const float*)d_in[4];
  const float* b2 = (const float*)d_in[5];
  float* out = (float*)d_out;

  char* ws = (char*)d_ws;
  // ws layout (bytes), all 256-aligned; total ~151.5 MB
  int*            counts   = (int*)(ws + 0);
  int*            top1cnt  = (int*)(ws + 32);
  float*          ssum     = (float*)(ws + 64);
  int*            h_off    = (int*)(ws + 96);
  int*            tile_off = (int*)(ws + 128);   // 9 ints
  int*            tok_list = (int*)(ws + 256);
  float*          wgt_list = (float*)(ws + 262400);
  unsigned short* x_bf     = (unsigned short*)(ws + 524544);
  unsigned short* w1t      = (unsigned short*)(ws + 17301760);
  unsigned short* w2t      = (unsigned short*)(ws + 50856192);
  unsigned short* h_buf    = (unsigned short*)(ws + 84410624);

  hipMemsetAsync(ws, 0, 256, stream);
  hipMemsetAsync(d_out, 0, (size_t)out_size * sizeof(float), stream);

  dim3 tb(32, 8);
  transpose_cast_kernel<<<dim3(HID / 32, DIM / 32, NE), tb, 0, stream>>>(w1, w1t, DIM, HID);
  transpose_cast_kernel<<<dim3(DIM / 32, HID / 32, NE), tb, 0, stream>>>(w2, w2t, HID, DIM);

  gate_kernel<<<T_TOK / GB_TOK, 256, 0, stream>>>(x, wg, x_bf, counts, top1cnt, ssum,
                                                  tok_list, wgt_list);
  scan_kernel<<<1, 64, 0, stream>>>(counts, top1cnt, ssum, h_off, tile_off,
                                    out + (size_t)T_TOK * DIM);

  // 1-D grids, multiples of 8 for the bijective XCD chunk swizzle:
  // GEMM1: 16 n-tiles x 136 flat m-tiles = 2176; GEMM2: 8 x 136 = 1088.
  moe_gemm_kernel<0><<<dim3((HID / BN) * 136), 256, 0, stream>>>(
      x_bf, w1t, b1, counts, h_off, tile_off, tok_list, wgt_list, h_buf, nullptr, HID, DIM);
  moe_gemm_kernel<1><<<dim3((DIM / BN) * 136), 256, 0, stream>>>(
      h_buf, w2t, b2, counts, h_off, tile_off, tok_list, wgt_list, nullptr, out, DIM, HID);
}